// Round 9
// baseline (117.774 us; speedup 1.0000x reference)
//
#include <hip/hip_runtime.h>
#include <hip/hip_bf16.h>

typedef _Float16 f16;
typedef _Float16 f16x8 __attribute__((ext_vector_type(8)));
typedef _Float16 f16x4 __attribute__((ext_vector_type(4)));
typedef float f32x4 __attribute__((ext_vector_type(4)));
typedef int i32x4 __attribute__((ext_vector_type(4)));

#define B_ 8
#define P_ 2048
#define Q_ 512
#define H_ 1024

__device__ __forceinline__ void gload_lds16(const void* g, void* l) {
  __builtin_amdgcn_global_load_lds(
      (const __attribute__((address_space(1))) void*)g,
      (__attribute__((address_space(3))) void*)l, 16, 0, 0);
}

// ---- f32 -> f16 convert (map_W) ----
__global__ __launch_bounds__(256) void k_cvt16(const float* __restrict__ x,
                                               f16* __restrict__ y, int n4) {
  int i = blockIdx.x * blockDim.x + threadIdx.x;
  int stride = gridDim.x * blockDim.x;
  for (; i < n4; i += stride) {
    f32x4 v = ((const f32x4*)x)[i];
    f16x4 h;
#pragma unroll
    for (int j = 0; j < 4; ++j) h[j] = (f16)v[j];
    ((f16x4*)y)[i] = h;
  }
}

// ---- question [B,Q,H] f32 -> qT [B,H,Q] f16 AND q16 [B,Q,H] f16 ----
__global__ __launch_bounds__(256) void k_transpose(const float* __restrict__ q,
                                                   f16* __restrict__ qT,
                                                   f16* __restrict__ q16) {
  __shared__ float t[64][65];
  int b = blockIdx.z;
  int h0 = blockIdx.x * 64, q0 = blockIdx.y * 64;
  int tid = threadIdx.x;
  int c4 = (tid & 15) * 4;
  int r16 = tid >> 4;
  const float* src = q + ((long)b * Q_ + q0) * H_ + h0;
  f16* d16 = q16 + ((long)b * Q_ + q0) * H_ + h0;
#pragma unroll
  for (int i = 0; i < 4; ++i) {
    int r = r16 + i * 16;
    f32x4 v = *(const f32x4*)(src + (long)r * H_ + c4);
    f16x4 s;
#pragma unroll
    for (int j = 0; j < 4; ++j) s[j] = (f16)v[j];
    *(f16x4*)(d16 + (long)r * H_ + c4) = s;
    t[c4 + 0][r] = v[0];
    t[c4 + 1][r] = v[1];
    t[c4 + 2][r] = v[2];
    t[c4 + 3][r] = v[3];
  }
  __syncthreads();
  f16* dst = qT + ((long)b * H_ + h0) * Q_ + q0;
#pragma unroll
  for (int i = 0; i < 4; ++i) {
    int hr = r16 + i * 16;
    f16x4 o;
#pragma unroll
    for (int j = 0; j < 4; ++j) o[j] = (f16)t[hr][c4 + j];
    *(f16x4*)(dst + (long)hr * Q_ + c4) = o;
  }
}

// ==== GEMM1: S = passage @ question^T, 128x128 tile, f16 in, f32 out ====
// 512 blocks (4 col x 16 row x 8 batch) -> 2 blocks/CU (LDS 48 KB,
// __launch_bounds__(512,4)): the R8 kernel's missing TLP — co-resident
// blocks' MFMAs fill each other's LDS-latency bubbles (m114).
// 512 thr / 8 waves (2M x 4N), wave tile 64x32, BK=32, NT=32.
// B (q16): 4-ring, 1 gload_lds/thread/tile, prefetch distance 3.
// A (passage f32): reg-staged 2 ahead, f32->f16 cvt, ds_write 1 ahead (T14).
// Steady-state wait vmcnt(4): forces B(t+1) (oldest) done; B(t+2),A(t+2),
// B(t+3) stay in flight. Batch == XCD (T1): question panel L2-resident.
__global__ __launch_bounds__(512, 4) void k_gemm1(
    const float* __restrict__ passage, const f16* __restrict__ q16,
    float* __restrict__ S) {
  constexpr int NT = H_ / 32;  // 32 K-tiles
  __shared__ __align__(16) f16 smem[24576];  // 48 KB: A 2x4096 + B 4x4096

  int orig = blockIdx.x;  // 512 blocks: gx=4 (col), gy=16 (row), z=8
  int wg = (orig & 7) * 64 + (orig >> 3);  // T1 bijective; z == XCD
  int bx = wg & 3, by = (wg >> 2) & 15, z = wg >> 6;
  int row0 = by * 128, col0 = bx * 128;

  int tid = threadIdx.x, wv = tid >> 6, lane = tid & 63;
  int fr = lane & 15, kq = lane >> 4;
  int wr = (wv >> 2) * 64, wc = (wv & 3) * 32;
  int swz = (kq ^ ((fr >> 1) & 3)) * 8;

  // A staging: row ar=tid>>2 (of 128), logical chunk ac=tid&3 (8 f32 each)
  int ar = tid >> 2, ac = tid & 3;
  const float* gA = passage + ((long)(z * P_ + row0 + ar)) * H_ + ac * 8;
  int aw = ar * 32 + ((ac ^ ((ar >> 1) & 3)) * 8);  // chunk-XOR swizzled

  // B staging: row tid>>2 (of 128), source chunk pre-swizzled (rule 21);
  // LDS dest linear (elem off = tid*8): one gload_lds16 per thread per tile.
  const f16* gB = q16 + ((long)(z * Q_ + col0 + (tid >> 2))) * H_ +
                  (((tid & 3) ^ ((tid >> 3) & 3)) * 8);

  auto stageB = [&](int t) {
    gload_lds16(gB + t * 32, smem + 8192 + (t & 3) * 4096 + wv * 512);
  };
  auto writeA = [&](int t, f32x4 lo, f32x4 hi) {
    f16x8 h;
#pragma unroll
    for (int j = 0; j < 4; ++j) {
      h[j] = (f16)lo[j];
      h[4 + j] = (f16)hi[j];
    }
    *(f16x8*)(smem + (t & 1) * 4096 + aw) = h;
  };

  f32x4 acc[4][2] = {};
  f32x4 a0lo, a0hi, a1lo, a1hi;  // named regs, static parity (rule 20)

  // prologue: A(0),A(1) -> regs; B(0..2) staged; A(0) -> LDS
  a0lo = *(const f32x4*)(gA);
  a0hi = *(const f32x4*)(gA + 4);
  a1lo = *(const f32x4*)(gA + 32);
  a1hi = *(const f32x4*)(gA + 36);
  stageB(0);
  stageB(1);
  stageB(2);
  writeA(0, a0lo, a0hi);  // implicit wait covers A(0) only
  asm volatile("s_waitcnt vmcnt(2) lgkmcnt(0)" ::: "memory");  // B(0) landed
  __builtin_amdgcn_s_barrier();
  __builtin_amdgcn_sched_barrier(0);

#pragma unroll 4
  for (int t = 0; t < NT; ++t) {
    if (t + 2 < NT) {  // A(t+2): parity (t+2)&1 == t&1
      const float* g = gA + (t + 2) * 32;
      if (t & 1) {
        a1lo = *(const f32x4*)(g);
        a1hi = *(const f32x4*)(g + 4);
      } else {
        a0lo = *(const f32x4*)(g);
        a0hi = *(const f32x4*)(g + 4);
      }
    }
    if (t + 3 < NT) stageB(t + 3);
    f16x8 af[4], bf[2];
    const f16* Ab = smem + (t & 1) * 4096;
    const f16* Bb = smem + 8192 + (t & 3) * 4096;
#pragma unroll
    for (int m = 0; m < 4; ++m)
      af[m] = *(const f16x8*)(Ab + (wr + m * 16 + fr) * 32 + swz);
#pragma unroll
    for (int n = 0; n < 2; ++n)
      bf[n] = *(const f16x8*)(Bb + (wc + n * 16 + fr) * 32 + swz);
    if (t + 1 < NT)  // A(t+1) parity: t even -> a1, t odd -> a0
      writeA(t + 1, (t & 1) ? a0lo : a1lo, (t & 1) ? a0hi : a1hi);
    __builtin_amdgcn_s_setprio(1);
#pragma unroll
    for (int m = 0; m < 4; ++m)
#pragma unroll
      for (int n = 0; n < 2; ++n)
        acc[m][n] = __builtin_amdgcn_mfma_f32_16x16x32_f16(af[m], bf[n],
                                                           acc[m][n], 0, 0, 0);
    __builtin_amdgcn_s_setprio(0);
    if (t <= NT - 4)
      asm volatile("s_waitcnt vmcnt(4) lgkmcnt(0)" ::: "memory");
    else if (t == NT - 3)
      asm volatile("s_waitcnt vmcnt(2) lgkmcnt(0)" ::: "memory");
    else
      asm volatile("s_waitcnt vmcnt(0) lgkmcnt(0)" ::: "memory");
    if (t < NT - 1) {
      __builtin_amdgcn_s_barrier();
      __builtin_amdgcn_sched_barrier(0);
    }
  }

  // epilogue: C/D layout col = lane&15, row = (lane>>4)*4 + j
  float* Sp = S + (long)z * P_ * Q_;
  int r0 = row0 + wr + (lane >> 4) * 4;
  int c0 = col0 + wc + fr;
#pragma unroll
  for (int m = 0; m < 4; ++m)
#pragma unroll
    for (int n = 0; n < 2; ++n)
#pragma unroll
      for (int j = 0; j < 4; ++j)
        Sp[(long)(r0 + m * 16 + j) * Q_ + c0 + n * 16] = acc[m][n][j];
}

// ---- masked softmax (R1-proven): alpha = m*e^{t-c}/(Sum(m*e) + 1e-13*Z) ----
__global__ __launch_bounds__(256) void k_softmax(const float* __restrict__ S,
                                                 const int* __restrict__ qmask,
                                                 f16* __restrict__ alpha) {
  int row = blockIdx.x * 4 + (threadIdx.x >> 6);
  int lane = threadIdx.x & 63;
  int b = row >> 11;  // P_=2048 rows per batch
  const float* s = S + (long)row * Q_;
  const int* mp = qmask + b * Q_;
  f32x4 v0 = ((const f32x4*)s)[lane * 2];
  f32x4 v1 = ((const f32x4*)s)[lane * 2 + 1];
  i32x4 m0 = ((const i32x4*)mp)[lane * 2];
  i32x4 m1 = ((const i32x4*)mp)[lane * 2 + 1];
  float t[8], mf[8];
#pragma unroll
  for (int j = 0; j < 4; ++j) {
    mf[j] = (float)m0[j];     t[j] = v0[j] * mf[j];
    mf[4 + j] = (float)m1[j]; t[4 + j] = v1[j] * mf[4 + j];
  }
  float mx = t[0];
#pragma unroll
  for (int j = 1; j < 8; ++j) mx = fmaxf(mx, t[j]);
  for (int o = 32; o; o >>= 1) mx = fmaxf(mx, __shfl_xor(mx, o, 64));
  float e[8], Z = 0.f, Sm = 0.f;
#pragma unroll
  for (int j = 0; j < 8; ++j) {
    e[j] = expf(t[j] - mx);
    Z += e[j];
    Sm += e[j] * mf[j];
  }
  for (int o = 32; o; o >>= 1) {
    Z += __shfl_xor(Z, o, 64);
    Sm += __shfl_xor(Sm, o, 64);
  }
  float inv = 1.0f / (Sm + 1e-13f * Z);
  f16x8 out;
#pragma unroll
  for (int j = 0; j < 8; ++j) out[j] = (f16)(e[j] * mf[j] * inv);
  *(f16x8*)(alpha + (long)row * Q_ + lane * 8) = out;
}

// ---- 256x256-tile deep-pipelined GEMM (R7/R8-proven), A[M,K]*B[N,K]^T ----
template <int EPI, int NT>
__global__ __launch_bounds__(512, 2) void k_gemm256(
    const f16* __restrict__ A, const f16* __restrict__ Bm,
    void* __restrict__ Cv, const float* __restrict__ bias, int N, int gx,
    int gy, long sA, long sB, long sC) {
  constexpr int K = NT * 32;
  __shared__ __align__(16) f16 smem[65536];

  int nwg = gridDim.x;  // 256
  int orig = blockIdx.x;
  int wg = (orig & 7) * (nwg >> 3) + (orig >> 3);  // T1 bijective
  int bx = wg % gx;
  int tt = wg / gx;
  int by = tt % gy;
  int z = tt / gy;
  int row0 = by * 256, col0 = bx * 256;
  A += z * sA;
  Bm += z * sB;

  int tid = threadIdx.x, wv = tid >> 6, lane = tid & 63;

  bool isA = wv < 4;
  int u0 = (wv & 3) * 4;
  int srow = u0 * 16 + (lane >> 2);
  int sclog = ((lane & 3) ^ ((lane >> 3) & 3)) * 8;
  const f16* sbaseG = isA ? A + (long)(row0 + srow) * K + sclog
                          : Bm + (long)(col0 + srow) * K + sclog;
  int sbaseL = (isA ? 0 : 8192) + u0 * 512;

  auto stage = [&](int tile) {
    const f16* g = sbaseG + (long)tile * 32;
    f16* l = smem + (tile & 3) * 16384 + sbaseL;
#pragma unroll
    for (int j = 0; j < 4; ++j) gload_lds16(g + (long)j * 16 * K, l + j * 512);
  };

  int wr = (wv >> 2) * 128, wc = (wv & 3) * 64;
  int fr = lane & 15, kq = lane >> 4;
  int swz = (kq ^ ((fr >> 1) & 3)) * 8 + fr * 32;

  f32x4 acc[8][4] = {};
  auto compute = [&](int t) {
    const f16* bufA = smem + (t & 3) * 16384;
    const f16* bufB = bufA + 8192;
    f16x8 af[8], bfr[4];
#pragma unroll
    for (int m = 0; m < 8; ++m)
      af[m] = *(const f16x8*)(bufA + (wr + m * 16) * 32 + swz);
#pragma unroll
    for (int n = 0; n < 4; ++n)
      bfr[n] = *(const f16x8*)(bufB + (wc + n * 16) * 32 + swz);
#pragma unroll
    for (int m = 0; m < 8; ++m)
#pragma unroll
      for (int n = 0; n < 4; ++n)
        acc[m][n] = __builtin_amdgcn_mfma_f32_16x16x32_f16(af[m], bfr[n],
                                                           acc[m][n], 0, 0, 0);
  };

  stage(0);
  stage(1);
  stage(2);
  asm volatile("s_waitcnt vmcnt(8)" ::: "memory");
  __builtin_amdgcn_s_barrier();
  __builtin_amdgcn_sched_barrier(0);
  for (int t = 0; t < NT - 3; ++t) {
    stage(t + 3);
    compute(t);
    asm volatile("s_waitcnt vmcnt(8)" ::: "memory");
    __builtin_amdgcn_s_barrier();
    __builtin_amdgcn_sched_barrier(0);
  }
  compute(NT - 3);
  asm volatile("s_waitcnt vmcnt(4)" ::: "memory");
  __builtin_amdgcn_s_barrier();
  __builtin_amdgcn_sched_barrier(0);
  compute(NT - 2);
  asm volatile("s_waitcnt vmcnt(0)" ::: "memory");
  __builtin_amdgcn_s_barrier();
  __builtin_amdgcn_sched_barrier(0);
  compute(NT - 1);

  int r0 = row0 + wr + (lane >> 4) * 4;
  int c0 = col0 + wc + fr;
  if constexpr (EPI == 1) {
    f16* C = (f16*)Cv + z * sC;
#pragma unroll
    for (int m = 0; m < 8; ++m)
#pragma unroll
      for (int n = 0; n < 4; ++n)
#pragma unroll
        for (int j = 0; j < 4; ++j)
          C[(long)(r0 + m * 16 + j) * N + c0 + n * 16] = (f16)acc[m][n][j];
  } else {
    float* C = (float*)Cv;
#pragma unroll
    for (int n = 0; n < 4; ++n) {
      float bv = bias[c0 + n * 16];
#pragma unroll
      for (int m = 0; m < 8; ++m)
#pragma unroll
        for (int j = 0; j < 4; ++j) {
          float v = acc[m][n][j] + bv;
          C[(long)(r0 + m * 16 + j) * N + c0 + n * 16] = fmaxf(v, 0.f);
        }
    }
  }
}

extern "C" void kernel_launch(void* const* d_in, const int* in_sizes, int n_in,
                              void* d_out, int out_size, void* d_ws,
                              size_t ws_size, hipStream_t stream) {
  const float* passage = (const float*)d_in[0];
  const float* question = (const float*)d_in[1];
  const int* qmask = (const int*)d_in[2];
  const float* mapW = (const float*)d_in[3];
  const float* mapb = (const float*)d_in[4];

  char* ws = (char*)d_ws;
  size_t off = 0;
  auto alloc = [&](size_t bytes) {
    void* p = ws + off;
    off += (bytes + 255) & ~(size_t)255;
    return p;
  };
  f16* q16 = (f16*)alloc((size_t)B_ * Q_ * H_ * 2);
  f16* qT = (f16*)alloc((size_t)B_ * H_ * Q_ * 2);
  f16* w16 = (f16*)alloc((size_t)H_ * H_ * 2);
  f16* alpha = (f16*)alloc((size_t)B_ * P_ * Q_ * 2);
  f16* O = (f16*)alloc((size_t)B_ * P_ * H_ * 2);
  float* S = (float*)alloc((size_t)B_ * P_ * Q_ * 4);

  k_cvt16<<<512, 256, 0, stream>>>(mapW, w16, H_ * H_ / 4);
  k_transpose<<<dim3(H_ / 64, Q_ / 64, B_), 256, 0, stream>>>(question, qT,
                                                              q16);

  // GEMM1: S = passage @ question^T  (4 x 16 x 8 = 512 tiles == 512 blocks)
  k_gemm1<<<512, 512, 0, stream>>>(passage, q16, S);

  // masked softmax -> alpha f16
  k_softmax<<<B_ * P_ / 4, 256, 0, stream>>>(S, qmask, alpha);

  // GEMM3: O = alpha @ question  (4 x 8 x 8 = 256 tiles == 256 blocks)
  k_gemm256<1, Q_ / 32><<<256, 512, 0, stream>>>(
      alpha, qT, O, nullptr, H_, H_ / 256, P_ / 256, (long)P_ * Q_,
      (long)H_ * Q_, (long)P_ * H_);

  // GEMM4: Y = relu(O @ W^T + b)  (4 x 64 x 1 = 256 tiles == 256 blocks)
  k_gemm256<2, H_ / 32><<<256, 512, 0, stream>>>(
      O, w16, d_out, mapb, H_, H_ / 256, (B_ * P_) / 256, 0, 0, 0);
}